// Round 7
// baseline (439.052 us; speedup 1.0000x reference)
//
#include <hip/hip_runtime.h>

#define NB    256               // batch
#define NT    512               // time steps
#define NF    33                // features incl. flag channel
#define BOND  64
#define NOUT  32
#define TC    64                // chunk length
#define NCH   (NT / TC)         // 8 chunks per batch
#define SLC   4096              // f16 per 64x64 slice (no pad; swizzle handles banks)

typedef _Float16 f16x4 __attribute__((ext_vector_type(4)));
typedef _Float16 f16x8 __attribute__((ext_vector_type(8)));
typedef float    f32x4 __attribute__((ext_vector_type(4)));

#define MFMA16(a, b, c) __builtin_amdgcn_mfma_f32_16x16x32_f16((a), (b), (c), 0, 0, 0)

// ---------------------------------------------------------------------------
// Phase 0: pack core channels f=1..32 into f16 MFMA A-fragment order,
// COLUMN-MAJOR flatten n' = j*64 + i (verbatim rounds 2-6, HW-verified):
//   cfrag[(nt*64 + l)*8 + m] = core[i][1+g*8+m][j], n' = nt*16+(l&15), i=n'&63, j=n'>>6.
// ---------------------------------------------------------------------------
__global__ __launch_bounds__(64) void pack_cfrag(const float* __restrict__ core,
                                                 _Float16* __restrict__ cfrag)
{
    int tid = blockIdx.x * 64 + threadIdx.x;      // 0 .. 16383
    int nt = tid >> 6, l = tid & 63;
    int g = l >> 4, c = l & 15;
    int n = nt * 16 + c;
    int i = n & 63, j = n >> 6;                   // column-major flatten
    const float* src = core + (size_t)i * (NF * BOND) + (size_t)(1 + g * 8) * BOND + j;
    f16x8 v;
    #pragma unroll
    for (int m = 0; m < 8; ++m) v[m] = (_Float16)src[(size_t)m * BOND];
    *(f16x8*)(cfrag + (size_t)tid * 8) = v;
}

// row-fragment load from a row-major swizzled 64x64 f16 buffer:
// lane (g,c): rows 16*row16 + c, k = kh*32 + 8g + m  (verified round-6 pattern)
__device__ __forceinline__ f16x8 ldf(const _Float16* base, int row16, int c, int kh,
                                     int g, int sw)
{
    return *(const f16x8*)(base + (row16 * 16 + c) * 64 + ((((kh) << 5) + (g << 3)) ^ sw));
}

// ---------------------------------------------------------------------------
// The verified product primitive (round-6 chain step, generalized):
//   W = V · U^T,  U/V row-major swizzled 64x64 f16 LDS buffers.
//   mfma(A = U-row-frag, B = V-row-frag):  lane (g,c) holds W[16Rb+c][16Cb+4g..+3]
//   -> vector b64 row-run writes (or f32x4 to global for the final apply).
// ALL reads hoisted before ANY write (safe for in-place O == U or O == V).
// ---------------------------------------------------------------------------
template<int NRB, int NCB, bool F32OUT>
__device__ __forceinline__ void prod_tiles(const _Float16* __restrict__ U,
                                           const _Float16* __restrict__ V,
                                           _Float16* O, float* FO,
                                           int rb0, int cb0, int g, int c, int sw)
{
    f16x8 uf[NCB][2], vf[NRB][2];
    #pragma unroll
    for (int cb = 0; cb < NCB; ++cb) {
        uf[cb][0] = ldf(U, cb0 + cb, c, 0, g, sw);
        uf[cb][1] = ldf(U, cb0 + cb, c, 1, g, sw);
    }
    #pragma unroll
    for (int rb = 0; rb < NRB; ++rb) {
        vf[rb][0] = ldf(V, rb0 + rb, c, 0, g, sw);
        vf[rb][1] = ldf(V, rb0 + rb, c, 1, g, sw);
    }
    #pragma unroll
    for (int rb = 0; rb < NRB; ++rb) {
        const int row = (rb0 + rb) * 16 + c;
        #pragma unroll
        for (int cb = 0; cb < NCB; ++cb) {
            f32x4 acc = {0.f, 0.f, 0.f, 0.f};
            acc = MFMA16(uf[cb][0], vf[rb][0], acc);
            acc = MFMA16(uf[cb][1], vf[rb][1], acc);
            const int col0 = (cb0 + cb) * 16 + (g << 2);
            if (F32OUT) {
                *(f32x4*)(FO + row * 64 + col0) = acc;
            } else {
                f16x4 hv;
                hv[0] = (_Float16)acc[0]; hv[1] = (_Float16)acc[1];   // RNE
                hv[2] = (_Float16)acc[2]; hv[3] = (_Float16)acc[3];
                *(f16x4*)(O + row * 64 + (col0 ^ sw)) = hv;
            }
        }
    }
}

// In-place MFMA transpose of one slice: plain M = I · (M^T)^T  (lossless: x*1.0).
// B-operand = synthesized identity row-fragment.
__device__ __forceinline__ void transpose_slice(_Float16* Sl, int g, int c, int sw)
{
    f16x8 uf[4][2];
    #pragma unroll
    for (int cb = 0; cb < 4; ++cb) {
        uf[cb][0] = ldf(Sl, cb, c, 0, g, sw);
        uf[cb][1] = ldf(Sl, cb, c, 1, g, sw);
    }
    #pragma unroll
    for (int rb = 0; rb < 4; ++rb) {
        const int row = rb * 16 + c;
        f16x8 iv[2];
        #pragma unroll
        for (int kh = 0; kh < 2; ++kh) {
            const int p = rb * 16 + c - (kh * 32 + g * 8);  // 1.0 goes at elem p
            #pragma unroll
            for (int m = 0; m < 8; ++m)
                iv[kh][m] = (_Float16)((p == m) ? 1.f : 0.f);
        }
        #pragma unroll
        for (int cb = 0; cb < 4; ++cb) {
            f32x4 acc = {0.f, 0.f, 0.f, 0.f};
            acc = MFMA16(uf[cb][0], iv[0], acc);
            acc = MFMA16(uf[cb][1], iv[1], acc);
            const int col0 = cb * 16 + (g << 2);
            f16x4 hv;
            hv[0] = (_Float16)acc[0]; hv[1] = (_Float16)acc[1];
            hv[2] = (_Float16)acc[2]; hv[3] = (_Float16)acc[3];
            *(f16x4*)(Sl + row * 64 + (col0 ^ sw)) = hv;
        }
    }
}

// ---------------------------------------------------------------------------
// Phase 1: per (batch, chunk): P = prod_t M_t via a product TREE per fr-group:
//   formation (16 M^T slices, verified) | T+L0 (transpose evens, 8 pair
//   products) | L1 (4 quads) | L2 (2) | L3 (Q16^T) | apply P <- P*Q16.
// Orientation rule: position-even outputs plain, position-odd transposed;
// every product needs (U = right^T-stored or plain per algebra, V = left).
// ---------------------------------------------------------------------------
__global__ __launch_bounds__(512, 1) void chunk_prod(const float* __restrict__ x,
                                                     const _Float16* __restrict__ cfrag,
                                                     float* __restrict__ Pout)
{
    __shared__ __align__(16) _Float16 Mb[16 * SLC];
    __shared__ __align__(16) _Float16 PB[2][64 * 64];
    __shared__ __align__(16) _Float16 Xl[TC][32];
    __shared__ float x0l[TC];

    const int tid = (int)threadIdx.x;
    const int l = tid & 63, w = tid >> 6;         // 8 waves
    const int g = l >> 4, c = l & 15;
    const int ch = (int)blockIdx.x, b = (int)blockIdx.y;
    const int sw = (c & 7) << 3;

    // ---- stage x chunk ----
    const float* xb = x + (size_t)b * (NT * NF) + (size_t)(ch * TC) * NF;
    for (int idx = tid; idx < TC * NF; idx += 512) {
        int t = idx / NF, f = idx - t * NF;
        float v = xb[idx];
        if (f == 0) x0l[t] = v;
        else        Xl[t][f - 1] = (_Float16)v;
    }
    // ---- P = I (row-major, swizzled) ----
    for (int idx = tid; idx < 4096; idx += 512) {
        int row = idx >> 6, col = idx & 63;
        PB[0][row * 64 + (col ^ ((row & 7) << 3))] = (row == col) ? (_Float16)1.f : (_Float16)0.f;
    }

    // ---- this wave's 32 cfrag tiles (compiler may re-load from L2; fine) ----
    f16x8 creg[32];
    {
        const _Float16* cf = cfrag + (size_t)w * 16384 + (size_t)l * 8;
        #pragma unroll
        for (int q = 0; q < 32; ++q) creg[q] = *(const f16x8*)(cf + (size_t)q * 512);
    }
    __syncthreads();

    int pcur = 0;
    float* Po = Pout + (size_t)(b * NCH + ch) * 4096;

    #pragma unroll 1
    for (int fr = 0; fr < 4; ++fr) {
        // ======== formation: M^T slices for t' = fr*16 + c (round-6 verbatim) ========
        f16x8 xa  = *(const f16x8*)&Xl[fr * 16 + c][g * 8];
        float x0v = x0l[fr * 16 + c];
        #pragma unroll
        for (int q = 0; q < 32; ++q) {
            int nt = w * 32 + q;
            f32x4 zero = {0.f, 0.f, 0.f, 0.f};
            f32x4 d = MFMA16(creg[q], xa, zero);
            int j  = nt >> 2;
            int i0 = ((nt & 3) << 4) + (g << 2);
            int dr = j - i0;                      // diag slot if 0..3
            f16x4 mv;
            mv[0] = (_Float16)((dr == 0) ? d[0] + x0v : d[0]);
            mv[1] = (_Float16)((dr == 1) ? d[1] + x0v : d[1]);
            mv[2] = (_Float16)((dr == 2) ? d[2] + x0v : d[2]);
            mv[3] = (_Float16)((dr == 3) ? d[3] + x0v : d[3]);
            *(f16x4*)(&Mb[c * SLC + (j << 6) + (i0 ^ ((j & 7) << 3))]) = mv;
        }
        __syncthreads();

        // ======== T + L0 (fused; wave w owns pair (2w, 2w+1), writes slice 2w) ======
        _Float16* Se = &Mb[(2 * w) * SLC];        // even slice -> plain M_2w (after T)
        _Float16* So = &Mb[(2 * w + 1) * SLC];    // odd slice  -> M^T_{2w+1}
        transpose_slice(Se, g, c, sw);            // in-place, own-wave only
        // Q1_w: even w -> plain (V = plain M_2w, U = mt_2w+1); odd w -> transposed (swap)
        if (w & 1) prod_tiles<4, 4, false>(Se, So, Se, nullptr, 0, 0, g, c, sw);
        else       prod_tiles<4, 4, false>(So, Se, Se, nullptr, 0, 0, g, c, sw);
        __syncthreads();

        // ======== L1: 4 quad products, 2 waves each; out slice 4k+1 ========
        {
            int k = w >> 1, h = w & 1;
            const _Float16* A = &Mb[(4 * k) * SLC];      // plain Q1_{2k}
            const _Float16* B = &Mb[(4 * k + 2) * SLC];  // Q1t_{2k+1}
            _Float16* O = &Mb[(4 * k + 1) * SLC];
            if (k & 1) prod_tiles<2, 4, false>(A, B, O, nullptr, 2 * h, 0, g, c, sw);
            else       prod_tiles<2, 4, false>(B, A, O, nullptr, 2 * h, 0, g, c, sw);
        }
        __syncthreads();

        // ======== L2: 2 products, 4 waves each; out slice 8p+3 ========
        {
            int p = w >> 2, h = w & 3;
            const _Float16* A = &Mb[(8 * p + 1) * SLC];  // plain Q4_{2p}
            const _Float16* B = &Mb[(8 * p + 5) * SLC];  // Q4t_{2p+1}
            _Float16* O = &Mb[(8 * p + 3) * SLC];
            if (p & 1) prod_tiles<1, 4, false>(A, B, O, nullptr, h, 0, g, c, sw);
            else       prod_tiles<1, 4, false>(B, A, O, nullptr, h, 0, g, c, sw);
        }
        __syncthreads();

        // ======== L3: Q16t = Q8_1^T * Q8_0^T  (U = plain Q8_0 s3, V = Q8t_1 s11) ====
        prod_tiles<1, 2, false>(&Mb[3 * SLC], &Mb[11 * SLC], &Mb[7 * SLC], nullptr,
                                w >> 1, 2 * (w & 1), g, c, sw);
        __syncthreads();

        // ======== apply: P <- P * Q16  (U = Q16t s7, V = P) ========
        if (fr == 3) {
            prod_tiles<1, 2, true>(&Mb[7 * SLC], &PB[pcur][0], nullptr, Po,
                                   w >> 1, 2 * (w & 1), g, c, sw);
        } else {
            prod_tiles<1, 2, false>(&Mb[7 * SLC], &PB[pcur][0], &PB[pcur ^ 1][0], nullptr,
                                    w >> 1, 2 * (w & 1), g, c, sw);
            pcur ^= 1;
        }
        __syncthreads();
    }
}

// ---------------------------------------------------------------------------
// Phase 2: per batch, v = alpha; v = v @ P_c for c=0..7; out = v @ output_core.
// ---------------------------------------------------------------------------
__global__ __launch_bounds__(256) void combine(const float* __restrict__ P,
                                               const float* __restrict__ alpha,
                                               const float* __restrict__ oc,
                                               float* __restrict__ out)
{
    const int b = (int)blockIdx.x;
    const int tid = (int)threadIdx.x, j = tid & 63, q = tid >> 6;   // q = 0..3
    __shared__ float vb[BOND];
    __shared__ float ps[4][BOND];
    if (tid < BOND) vb[tid] = alpha[tid];
    __syncthreads();
    for (int ch = 0; ch < NCH; ++ch) {
        const float* Pc = P + (size_t)(b * NCH + ch) * 4096;
        float s = 0.f;
        #pragma unroll
        for (int k = 0; k < 16; ++k) {
            int i = q * 16 + k;
            s = fmaf(vb[i], Pc[i * 64 + j], s);
        }
        ps[q][j] = s;
        __syncthreads();
        if (q == 0) vb[j] = (ps[0][j] + ps[1][j]) + (ps[2][j] + ps[3][j]);
        __syncthreads();
    }
    if (tid < NOUT) {
        float s = 0.f;
        #pragma unroll 8
        for (int i = 0; i < BOND; ++i) s = fmaf(vb[i], oc[i * NOUT + tid], s);
        out[b * NOUT + tid] = s;
    }
}

extern "C" void kernel_launch(void* const* d_in, const int* in_sizes, int n_in,
                              void* d_out, int out_size, void* d_ws, size_t ws_size,
                              hipStream_t stream)
{
    const float* x     = (const float*)d_in[0];  // (256, 512, 33) f32
    const float* core  = (const float*)d_in[1];  // (64, 33, 64) f32
    const float* alpha = (const float*)d_in[2];  // (64,) f32
    const float* oc    = (const float*)d_in[3];  // (64, 32) f32
    float* out = (float*)d_out;                  // (256, 32) f32

    // workspace: [cfrag f16: 262144 B][P f32: 256*8*4096*4 = 33554432 B]
    _Float16* cfrag = (_Float16*)d_ws;
    float*    P     = (float*)((char*)d_ws + 262144);

    pack_cfrag<<<dim3(256), dim3(64), 0, stream>>>(core, cfrag);
    chunk_prod<<<dim3(NCH, NB), dim3(512), 0, stream>>>(x, cfrag, P);
    combine<<<dim3(NB), dim3(256), 0, stream>>>(P, alpha, oc, out);
}

// Round 8
// 436.748 us; speedup vs baseline: 1.0053x; 1.0053x over previous
//
#include <hip/hip_runtime.h>

#define NB    256               // batch
#define NT    512               // time steps
#define NF    33                // features incl. flag channel
#define BOND  64
#define NOUT  32
#define TC    64                // chunk length
#define NCH   (NT / TC)         // 8 chunks per batch

typedef _Float16 f16x4 __attribute__((ext_vector_type(4)));
typedef _Float16 f16x8 __attribute__((ext_vector_type(8)));
typedef float    f32x4 __attribute__((ext_vector_type(4)));

#define MFMA16(a, b, c) __builtin_amdgcn_mfma_f32_16x16x32_f16((a), (b), (c), 0, 0, 0)

// ---------------------------------------------------------------------------
// Phase 0: pack core channels f=1..32 into f16 MFMA A-fragment order,
// COLUMN-MAJOR flatten n' = j*64 + i (verbatim rounds 4-6, HW-verified).
// ---------------------------------------------------------------------------
__global__ __launch_bounds__(64) void pack_cfrag(const float* __restrict__ core,
                                                 _Float16* __restrict__ cfrag)
{
    int tid = blockIdx.x * 64 + threadIdx.x;      // 0 .. 16383
    int nt = tid >> 6, l = tid & 63;
    int g = l >> 4, c = l & 15;
    int n = nt * 16 + c;
    int i = n & 63, j = n >> 6;                   // column-major flatten
    const float* src = core + (size_t)i * (NF * BOND) + (size_t)(1 + g * 8) * BOND + j;
    f16x8 v;
    #pragma unroll
    for (int m = 0; m < 8; ++m) v[m] = (_Float16)src[(size_t)m * BOND];
    *(f16x8*)(cfrag + (size_t)tid * 8) = v;
}

// ---------------------------------------------------------------------------
// Phase 1: wave-specialized. Waves 0-3: chain, P rows 16w..16w+15 in regs,
// per-step self-stage (round-6 PB addressing, wave-private => no barriers).
// Waves 4-7: form next round's 8 M^T slices into the other Mb half.
// M^T layout: slice sl, buffer-row j (M col), logical col i stored at
//   i ^ ((j&7)<<3) ^ (sl<<3)   (row-key XOR + slice-key XOR, stride 4096 f16).
// Barriers: stage-sync, then exactly 8 matched events:
//   formation: { form(g_k); sync }  |  chain: { sync; round(k) }.
// ---------------------------------------------------------------------------
__global__ __launch_bounds__(512, 2) void chunk_prod(const float* __restrict__ x,
                                                     const _Float16* __restrict__ cfrag,
                                                     float* __restrict__ Pout)
{
    __shared__ __align__(16) _Float16 Mb[2][8 * 4096];   // dbuf x 8 slices
    __shared__ __align__(16) _Float16 Pst[4][16 * 64];   // per-chain-wave stage
    __shared__ __align__(16) _Float16 Xl[TC * 32];
    __shared__ float x0l[TC];

    const int tid = (int)threadIdx.x;
    const int l = tid & 63, w = tid >> 6;         // 8 waves
    const int g = l >> 4, c = l & 15;
    const int ch = (int)blockIdx.x, b = (int)blockIdx.y;
    const int sw = (c & 7) << 3;

    // ---- stage x chunk ----
    const float* xb = x + (size_t)b * (NT * NF) + (size_t)(ch * TC) * NF;
    for (int idx = tid; idx < TC * NF; idx += 512) {
        int t = idx / NF, f = idx - t * NF;
        float v = xb[idx];
        if (f == 0) x0l[t] = v;
        else        Xl[t * 32 + (f - 1)] = (_Float16)v;
    }
    __syncthreads();                              // event 0

    if (w >= 4) {
        // ================= formation waves =================
        const int fw = w - 4;                     // 0..3, owns n-tiles fw*64..+63
        const int sl = c & 7, sx = sl << 3;       // slice = c&7 (cols c, c+8 dup)
        const _Float16* cf0 = cfrag + ((size_t)(fw * 64) * 64 + (size_t)l) * 8;
        f16x8 creg[32];                           // cache half the tiles in regs
        #pragma unroll
        for (int q = 0; q < 32; ++q) creg[q] = *(const f16x8*)(cf0 + (size_t)q * 512);

        #pragma unroll 1
        for (int gi = 0; gi < 8; ++gi) {          // group gi ready before round gi
            _Float16* Mg = Mb[gi & 1];
            f16x8 xa = *(const f16x8*)(Xl + (gi * 8 + sl) * 32 + 8 * g);
            float x0v = x0l[gi * 8 + sl];
            #pragma unroll
            for (int q = 0; q < 64; ++q) {
                int nt = fw * 64 + q;
                f16x8 ca = (q < 32) ? creg[q] : *(const f16x8*)(cf0 + (size_t)q * 512);
                f32x4 z = {0.f, 0.f, 0.f, 0.f};
                f32x4 d = MFMA16(ca, xa, z);      // lane: M[i0..i0+3][j], slice sl
                int j  = nt >> 2;
                int i0 = ((nt & 3) << 4) + (g << 2);
                int dr = j - i0;                  // diag slot if 0..3
                f16x4 mv;
                mv[0] = (_Float16)((dr == 0) ? d[0] + x0v : d[0]);   // RNE
                mv[1] = (_Float16)((dr == 1) ? d[1] + x0v : d[1]);
                mv[2] = (_Float16)((dr == 2) ? d[2] + x0v : d[2]);
                mv[3] = (_Float16)((dr == 3) ? d[3] + x0v : d[3]);
                *(f16x4*)(&Mg[sl * 4096 + (j << 6) + (i0 ^ ((j & 7) << 3) ^ sx)]) = mv;
            }
            __syncthreads();                      // events 1..8
        }
    } else {
        // ================= chain waves =================
        _Float16* Pw = &Pst[w][0];                // private 16x64 stage
        f16x8 a0, a1;                             // P[16w+c][kh*32+8g+m]
        #pragma unroll
        for (int m = 0; m < 8; ++m) {             // P = I (exact in f16)
            a0[m] = (_Float16)(((16 * w + c) == (8 * g + m)) ? 1.f : 0.f);
            a1[m] = (_Float16)(((16 * w + c) == (32 + 8 * g + m)) ? 1.f : 0.f);
        }
        f32x4 q0, q1, q2, q3;
        #pragma unroll 1
        for (int r = 0; r < 8; ++r) {
            __syncthreads();                      // events 1..8 (round r gated)
            const _Float16* Mg = Mb[r & 1];
            #pragma unroll
            for (int s = 0; s < 8; ++s) {
                const _Float16* Ms = Mg + s * 4096;
                const int kx0 = (8 * g) ^ sw ^ (s << 3);
                const int kx1 = kx0 ^ 32;
                f16x8 b00 = *(const f16x8*)(Ms + (c)      * 64 + kx0);
                f16x8 b01 = *(const f16x8*)(Ms + (c)      * 64 + kx1);
                f16x8 b10 = *(const f16x8*)(Ms + (16 + c) * 64 + kx0);
                f16x8 b11 = *(const f16x8*)(Ms + (16 + c) * 64 + kx1);
                f16x8 b20 = *(const f16x8*)(Ms + (32 + c) * 64 + kx0);
                f16x8 b21 = *(const f16x8*)(Ms + (32 + c) * 64 + kx1);
                f16x8 b30 = *(const f16x8*)(Ms + (48 + c) * 64 + kx0);
                f16x8 b31 = *(const f16x8*)(Ms + (48 + c) * 64 + kx1);
                f32x4 z = {0.f, 0.f, 0.f, 0.f};
                // swapped slots (round-6 verified): lane holds P'[16w+c][jb*16+4g+e]
                q0 = MFMA16(b00, a0, z); q0 = MFMA16(b01, a1, q0);
                q1 = MFMA16(b10, a0, z); q1 = MFMA16(b11, a1, q1);
                q2 = MFMA16(b20, a0, z); q2 = MFMA16(b21, a1, q2);
                q3 = MFMA16(b30, a0, z); q3 = MFMA16(b31, a1, q3);
                if (!(r == 7 && s == 7)) {
                    f16x4 h0, h1, h2, h3;         // RNE, as round 6
                    h0[0]=(_Float16)q0[0]; h0[1]=(_Float16)q0[1]; h0[2]=(_Float16)q0[2]; h0[3]=(_Float16)q0[3];
                    h1[0]=(_Float16)q1[0]; h1[1]=(_Float16)q1[1]; h1[2]=(_Float16)q1[2]; h1[3]=(_Float16)q1[3];
                    h2[0]=(_Float16)q2[0]; h2[1]=(_Float16)q2[1]; h2[2]=(_Float16)q2[2]; h2[3]=(_Float16)q2[3];
                    h3[0]=(_Float16)q3[0]; h3[1]=(_Float16)q3[1]; h3[2]=(_Float16)q3[2]; h3[3]=(_Float16)q3[3];
                    const int wc = (4 * g) ^ sw;  // row-key XOR store (row = c)
                    *(f16x4*)(Pw + c * 64 + wc)        = h0;
                    *(f16x4*)(Pw + c * 64 + (wc ^ 16)) = h1;
                    *(f16x4*)(Pw + c * 64 + (wc ^ 32)) = h2;
                    *(f16x4*)(Pw + c * 64 + (wc ^ 48)) = h3;
                    a0 = *(const f16x8*)(Pw + c * 64 + ((8 * g) ^ sw));
                    a1 = *(const f16x8*)(Pw + c * 64 + ((32 + 8 * g) ^ sw));
                }
            }
        }
        // final chunk product in f32 (pre-rounding), rows 16w+c
        float* Po = Pout + (size_t)(b * NCH + ch) * 4096;
        const int prow = 16 * w + c;
        *(f32x4*)(Po + prow * 64 +  0 + 4 * g) = q0;
        *(f32x4*)(Po + prow * 64 + 16 + 4 * g) = q1;
        *(f32x4*)(Po + prow * 64 + 32 + 4 * g) = q2;
        *(f32x4*)(Po + prow * 64 + 48 + 4 * g) = q3;
    }
}

// ---------------------------------------------------------------------------
// Phase 2: per batch, v = alpha; v = v @ P_c for c=0..7; out = v @ output_core.
// ---------------------------------------------------------------------------
__global__ __launch_bounds__(256) void combine(const float* __restrict__ P,
                                               const float* __restrict__ alpha,
                                               const float* __restrict__ oc,
                                               float* __restrict__ out)
{
    const int b = (int)blockIdx.x;
    const int tid = (int)threadIdx.x, j = tid & 63, q = tid >> 6;   // q = 0..3
    __shared__ float vb[BOND];
    __shared__ float ps[4][BOND];
    if (tid < BOND) vb[tid] = alpha[tid];
    __syncthreads();
    for (int ch = 0; ch < NCH; ++ch) {
        const float* Pc = P + (size_t)(b * NCH + ch) * 4096;
        float s = 0.f;
        #pragma unroll
        for (int k = 0; k < 16; ++k) {
            int i = q * 16 + k;
            s = fmaf(vb[i], Pc[i * 64 + j], s);
        }
        ps[q][j] = s;
        __syncthreads();
        if (q == 0) vb[j] = (ps[0][j] + ps[1][j]) + (ps[2][j] + ps[3][j]);
        __syncthreads();
    }
    if (tid < NOUT) {
        float s = 0.f;
        #pragma unroll 8
        for (int i = 0; i < BOND; ++i) s = fmaf(vb[i], oc[i * NOUT + tid], s);
        out[b * NOUT + tid] = s;
    }
}

extern "C" void kernel_launch(void* const* d_in, const int* in_sizes, int n_in,
                              void* d_out, int out_size, void* d_ws, size_t ws_size,
                              hipStream_t stream)
{
    const float* x     = (const float*)d_in[0];  // (256, 512, 33) f32
    const float* core  = (const float*)d_in[1];  // (64, 33, 64) f32
    const float* alpha = (const float*)d_in[2];  // (64,) f32
    const float* oc    = (const float*)d_in[3];  // (64, 32) f32
    float* out = (float*)d_out;                  // (256, 32) f32

    // workspace: [cfrag f16: 262144 B][P f32: 256*8*4096*4 = 33554432 B]
    _Float16* cfrag = (_Float16*)d_ws;
    float*    P     = (float*)((char*)d_ws + 262144);

    pack_cfrag<<<dim3(256), dim3(64), 0, stream>>>(core, cfrag);
    chunk_prod<<<dim3(NCH, NB), dim3(512), 0, stream>>>(x, cfrag, P);
    combine<<<dim3(NB), dim3(256), 0, stream>>>(P, alpha, oc, out);
}